// Round 4
// baseline (131.755 us; speedup 1.0000x reference)
//
#include <hip/hip_runtime.h>

// Keep the reference's exact fp32 arithmetic for d2: no FMA contraction.
#pragma clang fp contract(off)

#define NBATCH 256   // B*L
#define NPTS   512   // points per batch
#define JDIM   128   // logit dim
#define ROWS_T 8     // ypred rows per tile (8*512*4 = 16 KB), double-buffered
#define NTILE  (JDIM / ROWS_T)   // 16 tiles

// ---- prep: pack (x,y,z,||x||^2) per point into ws so the fused kernel can
// read it via wave-uniform s_load (SMEM/K$ pipe, off the LDS+VMEM pipes).
// Separate dispatch keeps K$ coherent with these vector writes.
__global__ __launch_bounds__(512) void prep_xyz4(
    const float* __restrict__ xyz, float4* __restrict__ xyz4)
{
    int i = blockIdx.x * 512 + threadIdx.x;        // 0 .. NBATCH*NPTS-1
    const float* xp = xyz + (size_t)i * 3;
    float x = xp[0], y = xp[1], z = xp[2];
    float sq = (x * x + y * y) + z * z;            // matches np.sum(x*x,-1)
    xyz4[i] = make_float4(x, y, z, sq);
}

// Grid: 512 blocks = 2 per batch; block b -> batch b>>1, point-half b&1.
// Block: 512 threads. Phase A: (sub = tid>>8) scans m-half for point n.
// Phase B: (role = tid>>8) 0 -> sim[n][argmax], 1 -> sim[n][argmin].
__global__ __launch_bounds__(512) void fused_loss_kernel(
    const float* __restrict__ ypred,   // [NBATCH, JDIM, NPTS]
    const float4* __restrict__ xyz4,   // [NBATCH, NPTS] (x,y,z,sq)
    float* __restrict__ partials)      // [2*NBATCH]
{
    __shared__ float tiles[2][ROWS_T * NPTS];   // 32 KB ping-pong
    __shared__ float maxv[2][256];  __shared__ int maxi[2][256];  // [sub][nl]
    __shared__ float minv[2][256];  __shared__ int mini[2][256];
    __shared__ float wred[8];

    const int tid  = threadIdx.x;      // 0..511
    const int nl   = tid & 255;
    const int sub  = tid >> 8;         // phase A: m-half; phase B: role
    const int bl   = blockIdx.x >> 1;
    const int h    = blockIdx.x & 1;   // point-half owned by this block
    const int n    = h * 256 + nl;     // global point id this thread owns

    const float* yp = ypred + (size_t)bl * JDIM * NPTS;

    // issue tile-0 ypred loads NOW; they land during phase A (VMEM overlap)
    const float4* s0 = (const float4*)yp;
    float4 t0a = s0[tid], t0b = s0[512 + tid];

    // per-lane own point (vector load, coalesced)
    const float4* xq = xyz4 + (size_t)bl * NPTS;
    const float4 pn = xq[n];

    // ---- Phase A: scan 256 m's, q via wave-uniform s_load (SMEM pipe) ----
    const int mbase = __builtin_amdgcn_readfirstlane(sub << 8);
    float bmax_e = -1.0f,   bmax_o = -1.0f;   int ima_e = 0, ima_o = 0;
    float bmin_e = 3.0e38f, bmin_o = 3.0e38f; int imi_e = 0, imi_o = 0;

    #pragma unroll 8
    for (int mm = 0; mm < 256; mm += 2) {
        int m = mbase + mm;
        float4 qe = xq[m];                 // uniform index -> s_load_dwordx8
        float4 qo = xq[m + 1];

        float de = (pn.w + qe.w) - 2.0f * ((pn.x * qe.x + pn.y * qe.y) + pn.z * qe.z);
        de = fmaxf(de, 0.0f);
        float dq = (pn.w + qo.w) - 2.0f * ((pn.x * qo.x + pn.y * qo.y) + pn.z * qo.z);
        dq = fmaxf(dq, 0.0f);

        bool ge = de > bmax_e;  ima_e = ge ? m     : ima_e;  bmax_e = ge ? de : bmax_e;
        bool go = dq > bmax_o;  ima_o = go ? m + 1 : ima_o;  bmax_o = go ? dq : bmax_o;

        float me = (de == 0.0f) ? 1.0e6f : de;   // mask self + exact dupes
        float mo = (dq == 0.0f) ? 1.0e6f : dq;
        bool le = me < bmin_e;  imi_e = le ? m     : imi_e;  bmin_e = le ? me : bmin_e;
        bool lo = mo < bmin_o;  imi_o = lo ? m + 1 : imi_o;  bmin_o = lo ? mo : bmin_o;
    }

    // merge even/odd with first-occurrence tiebreak (value, then lower index)
    {
        bool to = (bmax_o > bmax_e) || (bmax_o == bmax_e && ima_o < ima_e);
        maxv[sub][nl] = to ? bmax_o : bmax_e;
        maxi[sub][nl] = to ? ima_o  : ima_e;
        bool tn = (bmin_o < bmin_e) || (bmin_o == bmin_e && imi_o < imi_e);
        minv[sub][nl] = tn ? bmin_o : bmin_e;
        mini[sub][nl] = tn ? imi_o  : imi_e;
    }
    __syncthreads();

    // merge sub-halves: sub0 indices < sub1 indices, strict compare keeps sub0 on ties
    int partner;
    if (sub == 0) {   // role 0: argmax partner
        partner = (maxv[1][nl] > maxv[0][nl]) ? maxi[1][nl] : maxi[0][nl];
    } else {          // role 1: argmin partner
        partner = (minv[1][nl] < minv[0][nl]) ? mini[1][nl] : mini[0][nl];
    }

    // ---- Phase B: double-buffered ypred tiles, register prefetch ----
    float acc = 0.0f;
    {
        float4* dst = (float4*)tiles[0];   // tile-0 data already in registers
        dst[tid] = t0a;  dst[512 + tid] = t0b;
    }
    __syncthreads();

    for (int t = 0; t < NTILE; ++t) {
        float4 p0, p1;
        if (t + 1 < NTILE) {   // issue next tile's global loads before compute
            const float4* sn = (const float4*)(yp + (size_t)(t + 1) * ROWS_T * NPTS);
            p0 = sn[tid];  p1 = sn[512 + tid];
        }

        const float* buf = tiles[t & 1];
        #pragma unroll
        for (int r = 0; r < ROWS_T; ++r) {
            float a = buf[r * NPTS + n];        // stride-1, conflict-free
            float p = buf[r * NPTS + partner];  // random gather, ~2-4 way
            acc = fmaf(a, p, acc);
        }

        if (t + 1 < NTILE) {
            float4* dst = (float4*)tiles[(t + 1) & 1];
            dst[tid] = p0;  dst[512 + tid] = p1;
        }
        __syncthreads();
    }

    // signed contribution: role 0 adds sim@max, role 1 subtracts sim@min
    float c = sub ? -acc : acc;
    #pragma unroll
    for (int off = 32; off > 0; off >>= 1)
        c += __shfl_down(c, off);
    if ((tid & 63) == 0) wred[tid >> 6] = c;
    __syncthreads();
    if (tid == 0) {
        float s = 0.0f;
        #pragma unroll
        for (int w = 0; w < 8; ++w) s += wred[w];
        partials[blockIdx.x] = s;
    }
}

__global__ __launch_bounds__(512) void reduce_mean_kernel(
    const float* __restrict__ partials, float* __restrict__ out)
{
    float v = partials[threadIdx.x];   // 512 partials, 512 threads
    #pragma unroll
    for (int off = 32; off > 0; off >>= 1)
        v += __shfl_down(v, off);

    __shared__ float w[8];
    if ((threadIdx.x & 63) == 0) w[threadIdx.x >> 6] = v;
    __syncthreads();
    if (threadIdx.x == 0) {
        float s = 0.0f;
        #pragma unroll
        for (int i = 0; i < 8; ++i) s += w[i];
        out[0] = s * (1.0f / (float)(NBATCH * NPTS));
    }
}

extern "C" void kernel_launch(void* const* d_in, const int* in_sizes, int n_in,
                              void* d_out, int out_size, void* d_ws, size_t ws_size,
                              hipStream_t stream) {
    const float* ypred = (const float*)d_in[0];   // [8,32,128,512] f32
    const float* xyz   = (const float*)d_in[1];   // [8,32,512,3]  f32

    // ws layout: [0, 2 MB) xyz4 staging, then 512 partials
    float4* xyz4    = (float4*)d_ws;
    float* partials = (float*)((char*)d_ws + (size_t)NBATCH * NPTS * sizeof(float4));
    float* out      = (float*)d_out;

    prep_xyz4<<<NBATCH, 512, 0, stream>>>(xyz, xyz4);
    fused_loss_kernel<<<2 * NBATCH, 512, 0, stream>>>(ypred, xyz4, partials);
    reduce_mean_kernel<<<1, 512, 0, stream>>>(partials, out);
}

// Round 5
// 129.345 us; speedup vs baseline: 1.0186x; 1.0186x over previous
//
#include <hip/hip_runtime.h>

// Keep the reference's exact fp32 arithmetic for d2: no FMA contraction.
// d2 = (sqn + sqm) + dot' with dot' built from (-2x) pre-scaled components is
// bit-identical to ref's (sqn+sqm) - 2*dot: scaling by powers of 2 and
// negation commute with IEEE rounding.
#pragma clang fp contract(off)

#define NBATCH 256   // B*L
#define NPTS   512   // points per batch
#define JDIM   128   // logit dim
#define ROWS_T 8     // ypred rows per tile (8*512*4 = 16 KB), double-buffered
#define NTILE  (JDIM / ROWS_T)   // 16 tiles

// Grid: 512 blocks = 2 per batch; block b -> batch b>>1, point-half b&1.
// Phase A: thread owns 2 points (n0, n0+128), scans an m-quarter (sub = t>>7).
// Phase B: thread (nl = t&255, role = t>>8) computes sim[n][pidx[role][nl]].
__global__ __launch_bounds__(512) void fused_loss_kernel(
    const float* __restrict__ ypred,   // [NBATCH, JDIM, NPTS]
    const float* __restrict__ xyz,     // [NBATCH, NPTS, 3]
    float* __restrict__ partials)      // [2*NBATCH]
{
    __shared__ float tiles[2][ROWS_T * NPTS];   // 2 x 16 KB
    __shared__ int   pidx[2][256];              // [argmax/argmin][local point]
    __shared__ float wred[8];

    const int t  = threadIdx.x;        // 0..511
    const int bl = blockIdx.x >> 1;
    const int h  = blockIdx.x & 1;     // point-half owned by this block

    const float* yp = ypred + (size_t)bl * JDIM * NPTS;

    // issue tile-0 ypred loads NOW; they land during phase A (VMEM overlap)
    const float4* s0 = (const float4*)yp;
    float4 t0a = s0[t], t0b = s0[512 + t];

    // ---- stage scaled xyz: (-2x, -2y, -2z, sq); sq from raw vals, ref order
    float4* xyzS = (float4*)tiles[0];           // 8 KB
    {
        const float* xp = xyz + (size_t)bl * NPTS * 3 + 3 * t;
        float x = xp[0], y = xp[1], z = xp[2];
        float sq = (x * x + y * y) + z * z;     // matches np.sum(x*x,-1)
        xyzS[t] = make_float4(-2.0f * x, -2.0f * y, -2.0f * z, sq);
    }
    // phase-A merge scratch aliased into tiles[1] (dead once phase B starts)
    float* maxv = tiles[1];                     // [4][256]
    int*   maxi = (int*)(tiles[1] + 1024);
    float* minv = tiles[1] + 2048;
    int*   mini = (int*)(tiles[1] + 3072);

    __syncthreads();

    // ---- Phase A: 2 points/thread, m-quarter scan ----
    const int nl  = t & 127;
    const int sub = t >> 7;            // 0..3, wave-uniform (wave = 64 lanes)
    const int n0  = h * 256 + nl;      // owned points: n0 and n0+128
    float4 sv0 = xyzS[n0];
    float4 sv1 = xyzS[n0 + 128];
    const float x0 = -0.5f * sv0.x, y0 = -0.5f * sv0.y, z0 = -0.5f * sv0.z, q0 = sv0.w;
    const float x1 = -0.5f * sv1.x, y1 = -0.5f * sv1.y, z1 = -0.5f * sv1.z, q1 = sv1.w;

    const int mbase = sub * 128;
    float bmax0 = -1.0f,   bmax1 = -1.0f;
    float bmin0 = 3.0e38f, bmin1 = 3.0e38f;
    int ima0 = mbase, ima1 = mbase, imi0 = mbase, imi1 = mbase;

    #pragma unroll 4
    for (int mm = 0; mm < 128; ++mm) {
        int m = mbase + mm;
        float4 qv = xyzS[m];           // wave-uniform -> LDS broadcast (1 per 2 pts)

        float a0 = x0 * qv.x, b0 = y0 * qv.y, c0 = z0 * qv.z;
        float dt0 = (a0 + b0) + c0;              // == -(2*dot), exact scale
        float d20 = (q0 + qv.w) + dt0;           // bits == ref d2 (pre-clamp)
        float a1 = x1 * qv.x, b1 = y1 * qv.y, c1 = z1 * qv.z;
        float dt1 = (a1 + b1) + c1;
        float d21 = (q1 + qv.w) + dt1;

        // argmax on unclamped d2: winner is large-positive, clamp irrelevant
        bool g0 = d20 > bmax0; ima0 = g0 ? m : ima0; bmax0 = g0 ? d20 : bmax0;
        // argmin: ref masks clamp(d2)==0 <=> d2<=0; fold into the compare
        bool l0 = (d20 < bmin0) && (d20 > 0.0f);
        imi0 = l0 ? m : imi0; bmin0 = l0 ? d20 : bmin0;

        bool g1 = d21 > bmax1; ima1 = g1 ? m : ima1; bmax1 = g1 ? d21 : bmax1;
        bool l1 = (d21 < bmin1) && (d21 > 0.0f);
        imi1 = l1 ? m : imi1; bmin1 = l1 ? d21 : bmin1;
    }

    maxv[sub * 256 + nl]       = bmax0;  maxi[sub * 256 + nl]       = ima0;
    minv[sub * 256 + nl]       = bmin0;  mini[sub * 256 + nl]       = imi0;
    maxv[sub * 256 + nl + 128] = bmax1;  maxi[sub * 256 + nl + 128] = ima1;
    minv[sub * 256 + nl + 128] = bmin1;  mini[sub * 256 + nl + 128] = imi1;
    __syncthreads();

    // merge 4 m-quarters per point; sequential strict compare keeps the
    // lowest sub (= lowest m-range) on exact ties -> first-occurrence
    if (t < 256) {
        float bv = maxv[t]; int bi = maxi[t];
        float sv = minv[t]; int si = mini[t];
        #pragma unroll
        for (int s = 1; s < 4; ++s) {
            float v = maxv[s * 256 + t]; int i = maxi[s * 256 + t];
            bool w = v > bv; bi = w ? i : bi; bv = w ? v : bv;
            float u = minv[s * 256 + t]; int j = mini[s * 256 + t];
            bool x = u < sv; si = x ? j : si; sv = x ? u : sv;
        }
        pidx[0][t] = bi;
        pidx[1][t] = si;
    }
    __syncthreads();

    // ---- Phase B: double-buffered ypred tiles; a-stream from global (L2),
    // LDS serves only the random partner gathers ----
    const int nlB  = t & 255;
    const int role = t >> 8;           // 0 -> argmax partner, 1 -> argmin
    const int nB   = h * 256 + nlB;
    const int partner = pidx[role][nlB];
    const float* aG = yp + nB;         // a_j = aG[j*NPTS], coalesced per role

    {
        float4* dst = (float4*)tiles[0];   // tile-0 data already in registers
        dst[t] = t0a;  dst[512 + t] = t0b;
    }
    __syncthreads();

    float acc = 0.0f;
    for (int tt = 0; tt < NTILE; ++tt) {
        float4 p0, p1;
        if (tt + 1 < NTILE) {   // issue next tile's global loads before compute
            const float4* sn = (const float4*)(yp + (size_t)(tt + 1) * ROWS_T * NPTS);
            p0 = sn[t];  p1 = sn[512 + t];
        }

        const float* buf = tiles[tt & 1];
        const float* aT  = aG + (size_t)tt * ROWS_T * NPTS;
        #pragma unroll
        for (int r = 0; r < ROWS_T; ++r) {
            float a = aT[r * NPTS];              // global, coalesced, L2-hot
            float p = buf[r * NPTS + partner];   // LDS gather, ~2-4 way
            acc = fmaf(a, p, acc);
        }

        if (tt + 1 < NTILE) {
            float4* dst = (float4*)tiles[(tt + 1) & 1];
            dst[t] = p0;  dst[512 + t] = p1;
        }
        __syncthreads();
    }

    // signed contribution: role 0 adds sim@max, role 1 subtracts sim@min
    float c = role ? -acc : acc;
    #pragma unroll
    for (int off = 32; off > 0; off >>= 1)
        c += __shfl_down(c, off);
    if ((t & 63) == 0) wred[t >> 6] = c;
    __syncthreads();
    if (t == 0) {
        float s = 0.0f;
        #pragma unroll
        for (int w = 0; w < 8; ++w) s += wred[w];
        partials[blockIdx.x] = s;
    }
}

__global__ __launch_bounds__(512) void reduce_mean_kernel(
    const float* __restrict__ partials, float* __restrict__ out)
{
    float v = partials[threadIdx.x];   // 512 partials, 512 threads
    #pragma unroll
    for (int off = 32; off > 0; off >>= 1)
        v += __shfl_down(v, off);

    __shared__ float w[8];
    if ((threadIdx.x & 63) == 0) w[threadIdx.x >> 6] = v;
    __syncthreads();
    if (threadIdx.x == 0) {
        float s = 0.0f;
        #pragma unroll
        for (int i = 0; i < 8; ++i) s += w[i];
        out[0] = s * (1.0f / (float)(NBATCH * NPTS));
    }
}

extern "C" void kernel_launch(void* const* d_in, const int* in_sizes, int n_in,
                              void* d_out, int out_size, void* d_ws, size_t ws_size,
                              hipStream_t stream) {
    const float* ypred = (const float*)d_in[0];   // [8,32,128,512] f32
    const float* xyz   = (const float*)d_in[1];   // [8,32,512,3]  f32
    float* partials    = (float*)d_ws;            // 512 floats
    float* out         = (float*)d_out;           // scalar

    fused_loss_kernel<<<2 * NBATCH, 512, 0, stream>>>(ypred, xyz, partials);
    reduce_mean_kernel<<<1, 512, 0, stream>>>(partials, out);
}